// Round 1
// baseline (121.831 us; speedup 1.0000x reference)
//
#include <hip/hip_runtime.h>
#include <hip/hip_bf16.h>

#define NBINS 20
#define NCOPY 16

// boundaries = linspace(0.5, 1.0, 21) in float32
__device__ __constant__ float c_bounds[NBINS + 1] = {
    0.500f, 0.525f, 0.550f, 0.575f, 0.600f,
    0.625f, 0.650f, 0.675f, 0.700f, 0.725f,
    0.750f, 0.775f, 0.800f, 0.825f, 0.850f,
    0.875f, 0.900f, 0.925f, 0.950f, 0.975f,
    1.000f};

// ws layout: [0..19] conf_sum (float), [20..39] acc_sum (float), [40..59] count (uint)
__global__ void ece_accum(const float4* __restrict__ confs,
                          const float4* __restrict__ accs,
                          int n4,
                          float* __restrict__ g_conf,
                          float* __restrict__ g_acc,
                          unsigned int* __restrict__ g_cnt) {
    __shared__ float s_conf[NCOPY][NBINS];
    __shared__ float s_acc[NCOPY][NBINS];
    __shared__ unsigned int s_cnt[NCOPY][NBINS];
    __shared__ float lb[NBINS + 1];

    // init LDS
    for (int i = threadIdx.x; i < NCOPY * NBINS; i += blockDim.x) {
        (&s_conf[0][0])[i] = 0.0f;
        (&s_acc[0][0])[i] = 0.0f;
        (&s_cnt[0][0])[i] = 0u;
    }
    if (threadIdx.x <= NBINS) lb[threadIdx.x] = c_bounds[threadIdx.x];
    __syncthreads();

    const int copy = threadIdx.x & (NCOPY - 1);
    const int stride = gridDim.x * blockDim.x;

    for (int i = blockIdx.x * blockDim.x + threadIdx.x; i < n4; i += stride) {
        float4 c4 = confs[i];
        float4 a4 = accs[i];
#pragma unroll
        for (int j = 0; j < 4; ++j) {
            float c = (j == 0) ? c4.x : (j == 1) ? c4.y : (j == 2) ? c4.z : c4.w;
            float a = (j == 0) ? a4.x : (j == 1) ? a4.y : (j == 2) ? a4.z : a4.w;
            // valid iff 0.5 < c <= 1.0  (bin is (b[j], b[j+1]])
            if (c > 0.5f && c <= 1.0f) {
                float t = (c - 0.5f) * 40.0f;
                int bin = (int)t;
                if (bin > NBINS - 1) bin = NBINS - 1;
                // fixup to exact searchsorted(side='left') semantics:
                // need lb[bin] < c <= lb[bin+1]
                if (c <= lb[bin]) --bin;
                else if (c > lb[bin + 1]) ++bin;
                if (bin >= 0 && bin < NBINS) {
                    atomicAdd(&s_cnt[copy][bin], 1u);
                    atomicAdd(&s_conf[copy][bin], c);
                    atomicAdd(&s_acc[copy][bin], a);
                }
            }
        }
    }
    __syncthreads();

    // reduce the 16 copies, one global atomic per bin per block
    for (int b = threadIdx.x; b < NBINS; b += blockDim.x) {
        float cs = 0.0f, as = 0.0f;
        unsigned int ct = 0u;
#pragma unroll
        for (int k = 0; k < NCOPY; ++k) {
            cs += s_conf[k][b];
            as += s_acc[k][b];
            ct += s_cnt[k][b];
        }
        atomicAdd(&g_conf[b], cs);
        atomicAdd(&g_acc[b], as);
        atomicAdd(&g_cnt[b], ct);
    }
}

__global__ void ece_final(const float* __restrict__ g_conf,
                          const float* __restrict__ g_acc,
                          const unsigned int* __restrict__ g_cnt,
                          float* __restrict__ out,
                          float n_total) {
    if (threadIdx.x == 0 && blockIdx.x == 0) {
        float ece = 0.0f;
        for (int b = 0; b < NBINS; ++b) {
            float cnt = (float)g_cnt[b];
            if (cnt > 0.0f) {
                float avg_conf = g_conf[b] / cnt;
                float avg_acc = g_acc[b] / cnt;
                float prop = cnt / n_total;
                ece += fabsf(avg_conf - avg_acc) * prop;
            }
        }
        out[0] = ece;
    }
}

extern "C" void kernel_launch(void* const* d_in, const int* in_sizes, int n_in,
                              void* d_out, int out_size, void* d_ws, size_t ws_size,
                              hipStream_t stream) {
    const float* confs = (const float*)d_in[0];
    const float* accs = (const float*)d_in[1];
    const int n = in_sizes[0];          // 16,777,216 (divisible by 4)
    const int n4 = n / 4;

    float* g_conf = (float*)d_ws;
    float* g_acc = g_conf + NBINS;
    unsigned int* g_cnt = (unsigned int*)(g_acc + NBINS);

    // zero the 60 accumulator words every call (harness poisons ws once)
    hipMemsetAsync(d_ws, 0, (2 * NBINS) * sizeof(float) + NBINS * sizeof(unsigned int), stream);

    const int threads = 256;
    int blocks = 2048;
    if (blocks > (n4 + threads - 1) / threads) blocks = (n4 + threads - 1) / threads;

    ece_accum<<<blocks, threads, 0, stream>>>((const float4*)confs, (const float4*)accs,
                                              n4, g_conf, g_acc, g_cnt);
    ece_final<<<1, 64, 0, stream>>>(g_conf, g_acc, g_cnt, (float*)d_out, (float)n);
}

// Round 2
// 47.899 us; speedup vs baseline: 2.5435x; 2.5435x over previous
//
#include <hip/hip_runtime.h>
#include <hip/hip_bf16.h>

#define NBINS 20

// Accumulate per-bin sum of d = (conf - acc) into 20 per-thread REGISTER
// accumulators (static indexing only -> stays in VGPRs, rule #20).
// bin = ceil((c-0.5)*40) - 1 gives left-open/right-closed bins matching
// searchsorted(side='left') - 1. Invalid samples (c<=0.5 or c>1) map outside
// [0,20) and match no accumulator -> implicitly discarded, no branches.
__global__ void ece_accum(const float4* __restrict__ confs,
                          const float4* __restrict__ accs,
                          int n4,
                          float* __restrict__ partials,  // [NBINS][gridDim.x]
                          int nb) {
    float acc[NBINS];
#pragma unroll
    for (int b = 0; b < NBINS; ++b) acc[b] = 0.0f;

    const int tid = blockIdx.x * blockDim.x + threadIdx.x;
    const int stride = gridDim.x * blockDim.x;

    for (int i = tid; i < n4; i += stride) {
        float4 c4 = confs[i];
        float4 a4 = accs[i];
#pragma unroll
        for (int j = 0; j < 4; ++j) {
            float c = (j == 0) ? c4.x : (j == 1) ? c4.y : (j == 2) ? c4.z : c4.w;
            float a = (j == 0) ? a4.x : (j == 1) ? a4.y : (j == 2) ? a4.z : a4.w;
            float d = c - a;
            float t = (c - 0.5f) * 40.0f;
            unsigned int bin = (unsigned int)((int)__builtin_ceilf(t) - 1);
#pragma unroll
            for (int b = 0; b < NBINS; ++b)
                acc[b] += (bin == (unsigned int)b) ? d : 0.0f;
        }
    }

    // wave-level butterfly reduce each bin
#pragma unroll
    for (int b = 0; b < NBINS; ++b) {
#pragma unroll
        for (int m = 32; m >= 1; m >>= 1)
            acc[b] += __shfl_xor(acc[b], m, 64);
    }

    __shared__ float red[NBINS][4];
    const int wave = threadIdx.x >> 6;
    const int lane = threadIdx.x & 63;
    if (lane == 0) {
#pragma unroll
        for (int b = 0; b < NBINS; ++b) red[b][wave] = acc[b];
    }
    __syncthreads();

    // threads 0..19 each write one bin's block-partial (non-atomic)
    if (threadIdx.x < NBINS) {
        int b = threadIdx.x;
        float s = red[b][0] + red[b][1] + red[b][2] + red[b][3];
        partials[b * nb + blockIdx.x] = s;
    }
}

// One block: reduce nb partials per bin, ece = sum_b |d_b| / N
__global__ void ece_final(const float* __restrict__ partials,
                          float* __restrict__ out,
                          float inv_n, int nb) {
    float s[NBINS];
#pragma unroll
    for (int b = 0; b < NBINS; ++b) s[b] = 0.0f;

    const int tid = threadIdx.x;
    const int nb4 = nb >> 2;  // nb is a multiple of 4
#pragma unroll
    for (int b = 0; b < NBINS; ++b) {
        const float4* pb = (const float4*)(partials + b * nb);
        for (int k = tid; k < nb4; k += blockDim.x) {
            float4 v = pb[k];
            s[b] += (v.x + v.y) + (v.z + v.w);
        }
    }
#pragma unroll
    for (int b = 0; b < NBINS; ++b) {
#pragma unroll
        for (int m = 32; m >= 1; m >>= 1)
            s[b] += __shfl_xor(s[b], m, 64);
    }

    __shared__ float red[NBINS][4];
    const int wave = tid >> 6;
    const int lane = tid & 63;
    if (lane == 0) {
#pragma unroll
        for (int b = 0; b < NBINS; ++b) red[b][wave] = s[b];
    }
    __syncthreads();

    if (tid == 0) {
        float ece = 0.0f;
#pragma unroll
        for (int b = 0; b < NBINS; ++b) {
            float t = (red[b][0] + red[b][1]) + (red[b][2] + red[b][3]);
            ece += fabsf(t);
        }
        out[0] = ece * inv_n;
    }
}

extern "C" void kernel_launch(void* const* d_in, const int* in_sizes, int n_in,
                              void* d_out, int out_size, void* d_ws, size_t ws_size,
                              hipStream_t stream) {
    const float* confs = (const float*)d_in[0];
    const float* accs = (const float*)d_in[1];
    const int n = in_sizes[0];   // 16,777,216
    const int n4 = n / 4;

    // blocks: 8 per CU (full occupancy), capped so partials fit in ws
    int nb = 2048;
    int ws_cap = (int)(ws_size / (NBINS * sizeof(float)));
    ws_cap &= ~3;  // keep multiple of 4 for float4 reduce
    if (nb > ws_cap) nb = ws_cap;
    if (nb < 4) nb = 4;

    float* partials = (float*)d_ws;

    ece_accum<<<nb, 256, 0, stream>>>((const float4*)confs, (const float4*)accs,
                                      n4, partials, nb);
    ece_final<<<1, 256, 0, stream>>>(partials, (float*)d_out, 1.0f / (float)n, nb);
}